// Round 16
// baseline (144.786 us; speedup 1.0000x reference)
//
#include <hip/hip_runtime.h>

// Problem constants (fixed by setup_inputs: bs=8, N=M=4096, C=128)
#define BS 8
#define NN 4096
#define MM 4096
#define CC 128
#define XT 128            // x rows per block
#define YT 64             // y rows per tile
#define MH 1024           // y rows per block
#define NMT (MH / YT)     // 16 y-tiles per block
#define NXT (NN / XT)     // 32 x-tiles

#define FINF_BITS 0x7F800000u

typedef __attribute__((ext_vector_type(8))) short bf16x8;
typedef __attribute__((ext_vector_type(4))) float f32x4;

// RNE fp32 -> bf16 (inputs are finite normals)
__device__ inline ushort f2bf(float f) {
    unsigned u = __float_as_uint(f);
    unsigned r = (u + 0x7FFFu + ((u >> 16) & 1u)) >> 16;
    return (ushort)r;
}

// ---------------------------------------------------------------------------
// prep (y only): fp32->bf16 copy of set2 + exact fp32 y norms +
// rowmin/colmin=+inf + out=0. x is converted inside ch_tile.
// ---------------------------------------------------------------------------
__global__ void ch_prep(const float* __restrict__ y,
                        ushort* __restrict__ y16, float* __restrict__ yn,
                        unsigned* __restrict__ rowmin, unsigned* __restrict__ colmin,
                        float* __restrict__ out) {
    int gid = blockIdx.x * blockDim.x + threadIdx.x;
    size_t i = (size_t)gid * 4;

    float4 w = *(const float4*)(y + i);
    ushort4 p;
    p.x = f2bf(w.x); p.y = f2bf(w.y); p.z = f2bf(w.z); p.w = f2bf(w.w);
    *(ushort4*)(y16 + i) = p;
    float sy = w.x * w.x + w.y * w.y + w.z * w.z + w.w * w.w;

#pragma unroll
    for (int mask = 1; mask <= 16; mask <<= 1)
        sy += __shfl_xor(sy, mask, 64);
    if ((threadIdx.x & 31) == 0)
        yn[gid >> 5] = sy;

    if (gid < BS * NN) rowmin[gid] = FINF_BITS;
    if (gid < BS * MM) colmin[gid] = FINF_BITS;
    if (gid == 0) out[0] = 0.0f;
}

// stage one half-K slice of a 64-row y tile (64 rows x 64 k = 8 KB) via
// global_load_lds width-16; dest lane-order, source chunk-swizzled c^(r&7).
__device__ __forceinline__ void stage_y(const ushort* __restrict__ Yb,
                                        ushort* __restrict__ buf,
                                        int tile, int half, int tid, int wave) {
#pragma unroll
    for (int s = 0; s < 2; ++s) {
        int f = s * 256 + tid;           // 512 chunks = 64 rows x 8
        int r = f >> 3, cslot = f & 7;
        const ushort* g = Yb + (size_t)(tile * YT + r) * CC + half * 64 +
                          ((cslot ^ (r & 7)) * 8);
        ushort* l = buf + (size_t)(s * 256 + wave * 64) * 8;  // uniform; HW adds lane*16
        __builtin_amdgcn_global_load_lds(
            (const __attribute__((address_space(1))) void*)g,
            (__attribute__((address_space(3))) void*)l, 16, 0, 0);
    }
}

// ---------------------------------------------------------------------------
// main kernel (R16): R14 core with the LDS diet that unlocks 3 blocks/CU.
//  - LDS = xs 32K + ys 2x8K + rowtile/xnorm 1K = 50.1 KB -> 3 blocks/CU
//    (R14/R15's 74.75 KB capped at 2; LDS was the binding occupancy limit).
//  - MH=1024 -> 1024 blocks so 3 blocks/CU is actually fillable (512 could
//    never exceed 2/CU).
//  - coltile deleted: col d^2-mins quad-shuffle-reduced then atomicMin
//    DIRECTLY to global colmin per tile (R3-proven cheap; wm-duplicated).
//  - y staged in 8 KB half-K slices, double-buffered via global_load_lds,
//    one phase of prefetch distance; 32 barriers/block.
//  - Proven stack kept: 4 waves 2x2 quadrants i=4,j=2 acc=32 AGPR (R14),
//    chunk-swizzled bank-uniform LDS (R15 math), in-kernel x conv+norms
//    (R12), XCD-pinned grid (R13), no fences (R11), no launch_bounds
//    coercion (R5/R6).
// ---------------------------------------------------------------------------
__global__ __launch_bounds__(256) void ch_tile(
    const float* __restrict__ Xf, const ushort* __restrict__ Y,
    const float* __restrict__ yn,
    unsigned* __restrict__ rowmin, unsigned* __restrict__ colmin) {

    __shared__ ushort xs[XT * CC];       // 32 KB, chunk-swizzled (r&7)
    __shared__ ushort ys[2][YT * 64];    // 2 x 8 KB half-K slices, swizzled
    __shared__ unsigned rowtile[XT];     // 0.5 KB
    __shared__ float xnorm[XT];          // 0.5 KB

    const int b  = blockIdx.x;           // 0..7 -> XCD pin (linear id % 8 == b)
    const int xt = blockIdx.y;           // 0..31
    const int mh = blockIdx.z;           // 0..3
    const int n0 = xt * XT;
    const int m0 = mh * MH;
    const int tid  = threadIdx.x;
    const int wave = tid >> 6;           // 0..3
    const int lane = tid & 63;
    const int lc   = lane & 15;          // A/B row, C col
    const int quad = lane >> 4;          // k-chunk, C row group
    const int wm = wave >> 1;            // x half (0/1)
    const int wn = wave & 1;             // y half (0/1)

    const ushort* Yb = Y + ((size_t)b * MM + m0) * CC;

    // ---- stage x tile: fp32 -> bf16 -> swizzled LDS; norms too ----
    const float* Xb = Xf + ((size_t)b * NN + n0) * CC;
    {
        float psum[8];
#pragma unroll
        for (int s = 0; s < 8; ++s) {
            int flat = s * 256 + tid;    // 2048 chunks = 128 rows x 16
            int r = flat >> 4, c = flat & 15;
            float4 v0 = *(const float4*)(Xb + (size_t)r * CC + c * 8);
            float4 v1 = *(const float4*)(Xb + (size_t)r * CC + c * 8 + 4);
            ushort h[8] = {f2bf(v0.x), f2bf(v0.y), f2bf(v0.z), f2bf(v0.w),
                           f2bf(v1.x), f2bf(v1.y), f2bf(v1.z), f2bf(v1.w)};
            *(bf16x8*)(xs + r * CC + (c ^ (r & 7)) * 8) = *(bf16x8*)h;
            psum[s] = v0.x * v0.x + v0.y * v0.y + v0.z * v0.z + v0.w * v0.w +
                      v1.x * v1.x + v1.y * v1.y + v1.z * v1.z + v1.w * v1.w;
        }
#pragma unroll
        for (int mask = 1; mask <= 8; mask <<= 1)
#pragma unroll
            for (int s = 0; s < 8; ++s)
                psum[s] += __shfl_xor(psum[s], mask, 64);
        if ((tid & 15) == 0) {
#pragma unroll
            for (int s = 0; s < 8; ++s)
                xnorm[s * 16 + (tid >> 4)] = psum[s];
        }
    }
    if (tid < XT) rowtile[tid] = FINF_BITS;

    // ---- kick off the pipeline: tile 0, half 0 ----
    stage_y(Yb, ys[0], 0, 0, tid, wave);

    __syncthreads();   // drains x LDS writes + first y slice

    // persistent x norms for this wave's rows
    float xnp[4][4];
#pragma unroll
    for (int i = 0; i < 4; ++i) {
        float4 t = *(const float4*)(&xnorm[wm * 64 + i * 16 + quad * 4]);
        xnp[i][0] = t.x; xnp[i][1] = t.y; xnp[i][2] = t.z; xnp[i][3] = t.w;
    }
    float rm[4][4];
#pragma unroll
    for (int i = 0; i < 4; ++i)
#pragma unroll
        for (int r = 0; r < 4; ++r) rm[i][r] = __builtin_inff();

    const float* ynb = yn + (size_t)b * MM + m0;
    const int xrow = (wm * 64 + lc) * CC;
    const int yrow = (wn * 32 + lc) * 64;   // slice row stride = 64 ushorts
    const int xsw  = lc & 7;

#pragma unroll 1
    for (int t = 0; t < NMT; ++t) {
        float ynr[2];
        f32x4 acc[4][2];
        const f32x4 z = {0.f, 0.f, 0.f, 0.f};

#pragma unroll
        for (int h = 0; h < 2; ++h) {
            const int ph = 2 * t + h;
            if (ph) __syncthreads();     // slice ph staged; slice ph^1 free

            // prefetch next half-K slice into the other buffer
            const int nh = ph + 1;
            if (nh < 2 * NMT)
                stage_y(Yb, ys[nh & 1], nh >> 1, nh & 1, tid, wave);

            if (h == 0) {
#pragma unroll
                for (int j = 0; j < 2; ++j)
                    ynr[j] = ynb[t * YT + wn * 32 + j * 16 + lc];
            }

            const ushort* yl = ys[ph & 1];
#pragma unroll
            for (int s2 = 0; s2 < 2; ++s2) {
                const int g = h * 2 + s2;
                bf16x8 af[4], yf[2];
                const int cx = ((g * 4 + quad) ^ xsw) * 8;
                const int cy = ((s2 * 4 + quad) ^ xsw) * 8;
#pragma unroll
                for (int j = 0; j < 2; ++j)
                    yf[j] = *(const bf16x8*)(yl + yrow + j * 16 * 64 + cy);
#pragma unroll
                for (int i = 0; i < 4; ++i)
                    af[i] = *(const bf16x8*)(xs + xrow + i * 16 * CC + cx);
#pragma unroll
                for (int j = 0; j < 2; ++j)
#pragma unroll
                    for (int i = 0; i < 4; ++i)
                        acc[i][j] = __builtin_amdgcn_mfma_f32_16x16x32_bf16(
                            af[i], yf[j], (g == 0) ? z : acc[i][j], 0, 0, 0);
            }
        }

        // ---- epilogue: d^2 mins (sqrt/clamp deferred) ----
        float cmv[2];
#pragma unroll
        for (int j = 0; j < 2; ++j) cmv[j] = __builtin_inff();

#pragma unroll
        for (int i = 0; i < 4; ++i) {
#pragma unroll
            for (int j = 0; j < 2; ++j) {
                f32x4 a = acc[i][j];
#pragma unroll
                for (int r = 0; r < 4; ++r) {
                    float d2 = xnp[i][r] + fmaf(-2.0f, a[r], ynr[j]);
                    rm[i][r] = fminf(rm[i][r], d2);
                    cmv[j]   = fminf(cmv[j], d2);
                }
            }
        }

        // col reduce across quads, then DIRECT global atomicMin (no coltile)
#pragma unroll
        for (int mask = 16; mask <= 32; mask <<= 1)
#pragma unroll
            for (int j = 0; j < 2; ++j)
                cmv[j] = fminf(cmv[j], __shfl_xor(cmv[j], mask, 64));
        if (quad == 0) {
#pragma unroll
            for (int j = 0; j < 2; ++j)
                atomicMin(&colmin[(size_t)b * MM + m0 + t * YT + wn * 32 + j * 16 + lc],
                          __float_as_uint(fmaxf(cmv[j], 0.0f)));
        }
    }

    // ---- row mins: reduce across the 16 lc lanes, LDS atomic once ----
#pragma unroll
    for (int mask = 1; mask <= 8; mask <<= 1)
#pragma unroll
        for (int i = 0; i < 4; ++i)
#pragma unroll
            for (int r = 0; r < 4; ++r)
                rm[i][r] = fminf(rm[i][r], __shfl_xor(rm[i][r], mask, 64));
    if (lc == 0) {
#pragma unroll
        for (int i = 0; i < 4; ++i)
#pragma unroll
            for (int r = 0; r < 4; ++r)
                atomicMin(&rowtile[wm * 64 + i * 16 + quad * 4 + r],
                          __float_as_uint(fmaxf(rm[i][r], 0.0f)));
    }

    // ---- flush row minima with global atomics ----
    __syncthreads();
    if (tid < XT)
        atomicMin(&rowmin[(size_t)b * NN + n0 + tid], rowtile[tid]);
}

// ---------------------------------------------------------------------------
// finalize: total = (sum w1*sqrt(rowmin) + sum w2*sqrt(colmin)) / 2
// ---------------------------------------------------------------------------
__global__ void ch_finalize(const unsigned* __restrict__ rowmin,
                            const unsigned* __restrict__ colmin,
                            const float* __restrict__ w1,
                            const float* __restrict__ w2,
                            float* __restrict__ out) {
    int i = blockIdx.x * blockDim.x + threadIdx.x;
    int stride = gridDim.x * blockDim.x;
    float s = 0.f;
    for (int idx = i; idx < BS * NN; idx += stride)
        s += w1[idx] * sqrtf(__uint_as_float(rowmin[idx])) +
             w2[idx] * sqrtf(__uint_as_float(colmin[idx]));
#pragma unroll
    for (int off = 32; off > 0; off >>= 1) s += __shfl_down(s, off, 64);
    __shared__ float ls[4];
    int lane = threadIdx.x & 63, wv = threadIdx.x >> 6;
    if (lane == 0) ls[wv] = s;
    __syncthreads();
    if (threadIdx.x == 0) {
        float t = ls[0] + ls[1] + ls[2] + ls[3];
        atomicAdd(out, 0.5f * t);
    }
}

extern "C" void kernel_launch(void* const* d_in, const int* in_sizes, int n_in,
                              void* d_out, int out_size, void* d_ws, size_t ws_size,
                              hipStream_t stream) {
    const float* set1 = (const float*)d_in[0];
    const float* set2 = (const float*)d_in[1];
    const float* w1   = (const float*)d_in[2];
    const float* w2   = (const float*)d_in[3];
    float* out = (float*)d_out;

    // workspace layout (~8.5 MiB)
    ushort*   y16    = (ushort*)d_ws;                        // BS*MM*CC bf16 (8 MB)
    float*    yn     = (float*)(y16 + (size_t)BS * MM * CC); // 128 KB
    unsigned* rowmin = (unsigned*)(yn + BS * MM);            // 128 KB (d^2 bits)
    unsigned* colmin = rowmin + BS * NN;                     // 128 KB (d^2 bits)

    ch_prep<<<BS * MM * CC / 4 / 256, 256, 0, stream>>>(
        set2, y16, yn, rowmin, colmin, out);

    dim3 grid(BS, NXT, MM / MH);   // b fastest -> linear id % 8 == b == XCD
    ch_tile<<<grid, 256, 0, stream>>>(set1, y16, yn, rowmin, colmin);

    ch_finalize<<<64, 256, 0, stream>>>(rowmin, colmin, w1, w2, out);
}